// Round 1
// baseline (3832.352 us; speedup 1.0000x reference)
//
#include <hip/hip_runtime.h>
#include <stdint.h>

#define T_IN  128
#define T_OUT 50

typedef __bf16 bf16x8_t __attribute__((ext_vector_type(8)));
typedef __bf16 bf16x2_t __attribute__((ext_vector_type(2)));
typedef float  f32x4_t  __attribute__((ext_vector_type(4)));

__device__ __forceinline__ float fast_sigmoid(float x) {
    return __builtin_amdgcn_rcpf(1.0f + __expf(-x));
}
__device__ __forceinline__ float fast_tanh(float x) {
    return 1.0f - 2.0f * __builtin_amdgcn_rcpf(1.0f + __expf(2.0f * x));
}

// h-buffer row: 64 bf16 = 128B data, padded to 176B (16B-aligned, odd dword
// stride 44 -> <=4-way bank aliasing on b64 writes / b128 reads)
#define HROW_BYTES 176
#define HBUF_WAVE  (16 * HROW_BYTES)   // 2816 B per wave

// MFMA layout facts used (verified in learn_hip m89/m91/m120):
//   A  : A[m = lane&15][k = (lane>>4)*8 + j]   (8 bf16 / lane)
//   B  : B[k = (lane>>4)*8 + j][n = lane&15]
//   C/D: col = lane&15, row = (lane>>4)*4 + reg
// k-permutation pi(p) = (p>>2) + 16*(p&3) applied identically to Whh columns
// and h columns (dot product invariant under shared k-permutation).

__global__ __launch_bounds__(256, 2) void seq2seq_lstm(
    const float* __restrict__ in_seq,
    const float* __restrict__ WihE, const float* __restrict__ WhhE,
    const float* __restrict__ bihE, const float* __restrict__ bhhE,
    const float* __restrict__ WihD, const float* __restrict__ WhhD,
    const float* __restrict__ bihD, const float* __restrict__ bhhD,
    const float* __restrict__ Wfc,  const float* __restrict__ bfc,
    float* __restrict__ out)
{
    __shared__ __align__(16) uint8_t sFragE[32768];   // enc Whh B-frags (bf16)
    __shared__ __align__(16) uint8_t sFragD[32768];   // dec Whh B-frags
    __shared__ __align__(16) uint8_t sHbuf[4 * HBUF_WAVE];

    const int tid  = threadIdx.x;
    const int lane = tid & 63;
    const int wave = tid >> 6;
    const int c    = lane & 15;   // n for B / col for C/D / m for A reads
    const int q    = lane >> 4;   // quad

    // ---- one-time: stage pre-swizzled, k-permuted Whh fragments ----
    for (int ph = 0; ph < 2; ++ph) {
        const float* W = ph ? WhhD : WhhE;
        uint8_t* dst   = ph ? sFragD : sFragE;
        #pragma unroll 1
        for (int it = 0; it < 8; ++it) {
            int idx = it * 256 + tid;   // 0..2047 = frag(0..31) x lane(0..63)
            int ln  = idx & 63;
            int fg  = idx >> 6;         // fg = tile*2 + kf
            int kf  = fg & 1;
            int t   = fg >> 1;
            int n   = ln & 15;
            int qq  = ln >> 4;
            const float* wr = W + (t * 16 + n) * 64;   // gate row 16t+n
            uint32_t wv[4];
            #pragma unroll
            for (int jj = 0; jj < 4; ++jj) {
                int p0 = kf * 32 + qq * 8 + 2 * jj;    // permuted positions
                int p1 = p0 + 1;
                int k0 = (p0 >> 2) + 16 * (p0 & 3);    // original k
                int k1 = (p1 >> 2) + 16 * (p1 & 3);
                bf16x2_t v = { (__bf16)wr[k0], (__bf16)wr[k1] };
                wv[jj] = __builtin_bit_cast(uint32_t, v);
            }
            uint32_t* d = (uint32_t*)(dst + fg * 1024 + ln * 16);
            d[0] = wv[0]; d[1] = wv[1]; d[2] = wv[2]; d[3] = wv[3];
        }
    }
    // h0 = 0
    for (int i = tid; i < (4 * HBUF_WAVE) / 4; i += 256)
        ((uint32_t*)sHbuf)[i] = 0u;
    __syncthreads();
    // ---- no barriers from here on: each wave owns its 16 batch rows ----

    uint8_t* hb = sHbuf + wave * HBUF_WAVE;
    const int rowBase = blockIdx.x * 64 + wave * 16;

    // per-lane column constants (fp32): bias and Wih for gate cols 16t+c
    float colB[16], wx0[16], wx1[16];
    #pragma unroll
    for (int t = 0; t < 16; ++t) {
        int n = t * 16 + c;
        colB[t] = bihE[n] + bhhE[n];
        float2 wv = *(const float2*)(WihE + n * 2);
        wx0[t] = wv.x; wx1[t] = wv.y;
    }

    f32x4_t cst[4];   // c state, C-layout: cst[tc][r] = c[row 4q+r][col c+16tc]
    f32x4_t hst[4];   // h (fp32, this step)
    #pragma unroll
    for (int tc = 0; tc < 4; ++tc) cst[tc] = (f32x4_t){0.f, 0.f, 0.f, 0.f};

    float x0[4], x1[4];   // x inputs for rows 4q+0..3 (fp32)

    auto lstm_step = [&](const uint8_t* frags) {
        // A-fragments: row m = c of this wave's h buffer
        const uint8_t* hrow = hb + c * HROW_BYTES;
        bf16x8_t a0 = *(const bf16x8_t*)(hrow + q * 16);        // perm pos 8q..8q+7
        bf16x8_t a1 = *(const bf16x8_t*)(hrow + 64 + q * 16);   // perm pos 32+8q..

        f32x4_t acc[16];
        #pragma unroll
        for (int t = 0; t < 16; ++t) {
            bf16x8_t b0 = *(const bf16x8_t*)(frags + (2 * t) * 1024 + lane * 16);
            bf16x8_t b1 = *(const bf16x8_t*)(frags + (2 * t + 1) * 1024 + lane * 16);
            f32x4_t z = {0.f, 0.f, 0.f, 0.f};
            acc[t] = __builtin_amdgcn_mfma_f32_16x16x32_bf16(a0, b0, z, 0, 0, 0);
            acc[t] = __builtin_amdgcn_mfma_f32_16x16x32_bf16(a1, b1, acc[t], 0, 0, 0);
        }
        // fp32 epilogue: bias + Wih*x
        #pragma unroll
        for (int t = 0; t < 16; ++t) {
            #pragma unroll
            for (int r = 0; r < 4; ++r)
                acc[t][r] += colB[t] + wx0[t] * x0[r] + wx1[t] * x1[r];
        }
        // activations + state update (gate tiles: i=0..3, f=4..7, g=8..11, o=12..15)
        #pragma unroll
        for (int tc = 0; tc < 4; ++tc) {
            #pragma unroll
            for (int r = 0; r < 4; ++r) {
                float ig = fast_sigmoid(acc[tc][r]);
                float fg = fast_sigmoid(acc[tc + 4][r]);
                float gg = fast_tanh(acc[tc + 8][r]);
                float og = fast_sigmoid(acc[tc + 12][r]);
                float cn = fg * cst[tc][r] + ig * gg;
                cst[tc][r] = cn;
                hst[tc][r] = og * fast_tanh(cn);
            }
        }
        // store h as bf16 at permuted positions 4c+tc -> bytes 8c..8c+7 of row 4q+r
        #pragma unroll
        for (int r = 0; r < 4; ++r) {
            bf16x2_t lo = { (__bf16)hst[0][r], (__bf16)hst[1][r] };
            bf16x2_t hi = { (__bf16)hst[2][r], (__bf16)hst[3][r] };
            uint2 u;
            u.x = __builtin_bit_cast(uint32_t, lo);
            u.y = __builtin_bit_cast(uint32_t, hi);
            *(uint2*)(hb + (4 * q + r) * HROW_BYTES + c * 8) = u;
        }
    };

    // ================= encoder: 128 steps =================
    #pragma unroll 1
    for (int t = 0; t < T_IN; ++t) {
        #pragma unroll
        for (int r = 0; r < 4; ++r) {
            float2 xv = *(const float2*)(in_seq +
                        ((size_t)(rowBase + 4 * q + r) * T_IN + t) * 2);
            x0[r] = xv.x; x1[r] = xv.y;
        }
        lstm_step(sFragE);
    }
    // x now holds input_seq[:, -1]  == dec_in0

    // switch constants to decoder
    #pragma unroll
    for (int t = 0; t < 16; ++t) {
        int n = t * 16 + c;
        colB[t] = bihD[n] + bhhD[n];
        float2 wv = *(const float2*)(WihD + n * 2);
        wx0[t] = wv.x; wx1[t] = wv.y;
    }
    float wf0[4], wf1[4];
    #pragma unroll
    for (int tc = 0; tc < 4; ++tc) {
        wf0[tc] = Wfc[c + 16 * tc];        // Wfc[0][col]
        wf1[tc] = Wfc[64 + c + 16 * tc];   // Wfc[1][col]
    }
    const float bfc0 = bfc[0], bfc1 = bfc[1];

    // ================= decoder: 50 steps =================
    #pragma unroll 1
    for (int td = 0; td < T_OUT; ++td) {
        lstm_step(sFragD);
        // fc: per-lane partial over this lane's 4 h columns, then 16-lane butterfly
        float s0[4], s1[4];
        #pragma unroll
        for (int r = 0; r < 4; ++r) {
            s0[r] = hst[0][r]*wf0[0] + hst[1][r]*wf0[1] + hst[2][r]*wf0[2] + hst[3][r]*wf0[3];
            s1[r] = hst[0][r]*wf1[0] + hst[1][r]*wf1[1] + hst[2][r]*wf1[2] + hst[3][r]*wf1[3];
        }
        #pragma unroll
        for (int m = 1; m <= 8; m <<= 1) {
            #pragma unroll
            for (int r = 0; r < 4; ++r) {
                s0[r] += __shfl_xor(s0[r], m, 64);
                s1[r] += __shfl_xor(s1[r], m, 64);
            }
        }
        #pragma unroll
        for (int r = 0; r < 4; ++r) {
            x0[r] = fast_sigmoid(s0[r] + bfc0);   // point -> next x
            x1[r] = fast_sigmoid(s1[r] + bfc1);
        }
        if (c == 0) {   // one lane per quad writes its 4 rows
            #pragma unroll
            for (int r = 0; r < 4; ++r) {
                float2 pv; pv.x = x0[r]; pv.y = x1[r];
                *(float2*)(out + ((size_t)(rowBase + 4 * q + r) * T_OUT + td) * 2) = pv;
            }
        }
    }
}

extern "C" void kernel_launch(void* const* d_in, const int* in_sizes, int n_in,
                              void* d_out, int out_size, void* d_ws, size_t ws_size,
                              hipStream_t stream) {
    const float* in_seq = (const float*)d_in[0];
    const float* WihE = (const float*)d_in[1];
    const float* WhhE = (const float*)d_in[2];
    const float* bihE = (const float*)d_in[3];
    const float* bhhE = (const float*)d_in[4];
    const float* WihD = (const float*)d_in[5];
    const float* WhhD = (const float*)d_in[6];
    const float* bihD = (const float*)d_in[7];
    const float* bhhD = (const float*)d_in[8];
    const float* Wfc  = (const float*)d_in[9];
    const float* bfcp = (const float*)d_in[10];
    float* out = (float*)d_out;

    const int B = in_sizes[0] / (T_IN * 2);   // 131072
    dim3 grid(B / 64), block(256);            // 64 rows/block (4 waves x 16)
    hipLaunchKernelGGL(seq2seq_lstm, grid, block, 0, stream,
                       in_seq, WihE, WhhE, bihE, bhhE,
                       WihD, WhhD, bihD, bhhD, Wfc, bfcp, out);
}